// Round 1
// baseline (438.810 us; speedup 1.0000x reference)
//
#include <hip/hip_runtime.h>
#include <hip/hip_bf16.h>
#include <cstdint>
#include <cstddef>

#define D_MODEL 1024
#define D_FF    4096
#define RANK    16
#define NTOK    16384   // B*S = 8*2048

typedef __attribute__((ext_vector_type(8))) __bf16 bf16x8;
typedef __attribute__((ext_vector_type(4))) float  f32x4;

using gas_t = const __attribute__((address_space(1))) void*;
using las_t = __attribute__((address_space(3))) void*;

__device__ __forceinline__ unsigned short f2bf(float f) {
    unsigned int u = __builtin_bit_cast(unsigned int, f);
    u += 0x7fffu + ((u >> 16) & 1u);
    return (unsigned short)(u >> 16);
}

__device__ __forceinline__ void gload_lds16(const unsigned short* g, unsigned short* l) {
    __builtin_amdgcn_global_load_lds((gas_t)g, (las_t)l, 16, 0, 0);
}

// ---- fp32 -> bf16 cast, vectorized ----
__global__ void cast_kernel(const float* __restrict__ in, unsigned short* __restrict__ out, int n4) {
    int i = blockIdx.x * blockDim.x + threadIdx.x;
    int stride = gridDim.x * blockDim.x;
    for (; i < n4; i += stride) {
        float4 v = reinterpret_cast<const float4*>(in)[i];
        ushort4 o;
        o.x = f2bf(v.x); o.y = f2bf(v.y); o.z = f2bf(v.z); o.w = f2bf(v.w);
        reinterpret_cast<ushort4*>(out)[i] = o;
    }
}

// ---- t_k[m][r] = sum_d h[m][d] * A_{idx_k}[r][d], packed [t0|t1] per row, bf16 ----
__global__ void lora_t_kernel(const float* __restrict__ h, const float* __restrict__ As,
                              const int* __restrict__ idx, unsigned short* __restrict__ tcat) {
    const int m = blockIdx.x;
    const int l = threadIdx.x;
    float hreg[16];
    #pragma unroll
    for (int j = 0; j < 16; ++j) hreg[j] = h[(size_t)m * D_MODEL + j * 64 + l];
    #pragma unroll
    for (int e = 0; e < 2; ++e) {
        const float* A = As + (size_t)idx[e] * RANK * D_MODEL;
        for (int r = 0; r < RANK; ++r) {
            float s = 0.f;
            #pragma unroll
            for (int j = 0; j < 16; ++j) s += hreg[j] * A[r * D_MODEL + j * 64 + l];
            #pragma unroll
            for (int off = 32; off >= 1; off >>= 1) s += __shfl_xor(s, off, 64);
            if (l == 0) tcat[(size_t)m * 32 + e * 16 + r] = f2bf(s);
        }
    }
}

// ---- Bcat[f][e*16+r] = bf16(lora_Bs[idx_e][f][r]) ----
__global__ void bcat_kernel(const float* __restrict__ Bs, const int* __restrict__ idx,
                            unsigned short* __restrict__ bcat) {
    int i = blockIdx.x * blockDim.x + threadIdx.x;   // over D_FF*32
    if (i >= D_FF * 32) return;
    int f = i >> 5, kk = i & 31;
    int e = kk >> 4, r = kk & 15;
    bcat[i] = f2bf(Bs[(size_t)idx[e] * D_FF * RANK + (size_t)f * RANK + r]);
}

// ---- 128x128 tile GEMM, A[M][K] x B[N][K]^T, bf16 MFMA 16x16x32 ----
// EPI==1: epilogue adds LoRA (via masked MFMA on packed [t0|t1]/[B0|B1]),
//         relu per expert, combines with v0/v1, stores bf16 to outBf.
// EPI==0: stores fp32 accumulator to outF.
template<int KDIM, int EPI, int OSTRIDE>
__launch_bounds__(256, 2)
__global__ void gemm_bt(const unsigned short* __restrict__ A,
                        const unsigned short* __restrict__ Bm,
                        float* __restrict__ outF,
                        unsigned short* __restrict__ outBf,
                        const unsigned short* __restrict__ tcat,
                        const unsigned short* __restrict__ bcat,
                        const float* __restrict__ topv) {
    __shared__ unsigned short lds[2][128 * 32];   // 8KB A-tile + 8KB B-tile
    const int tid  = threadIdx.x;
    const int lane = tid & 63;
    const int wid  = tid >> 6;
    const int wr = wid >> 1, wc = wid & 1;
    const int bm0 = blockIdx.x * 128;
    const int bn0 = blockIdx.y * 128;

    f32x4 acc[4][4] = {};

    for (int kt = 0; kt < KDIM / 32; ++kt) {
        const int k0 = kt * 32;
        #pragma unroll
        for (int p = 0; p < 2; ++p) {
            const int off = tid * 16 + p * 4096;      // byte offset into 8KB tile
            const int r   = off >> 6;                 // row (64B per row of 32 bf16)
            const int ce  = (off & 63) >> 1;          // element col
            gload_lds16(A  + (size_t)(bm0 + r) * KDIM + k0 + ce, &lds[0][0] + (off >> 1));
            gload_lds16(Bm + (size_t)(bn0 + r) * KDIM + k0 + ce, &lds[1][0] + (off >> 1));
        }
        __syncthreads();
        bf16x8 af[4], bfr[4];
        #pragma unroll
        for (int mi = 0; mi < 4; ++mi)
            af[mi] = *reinterpret_cast<const bf16x8*>(
                &lds[0][(wr * 64 + mi * 16 + (lane & 15)) * 32 + (lane >> 4) * 8]);
        #pragma unroll
        for (int ni = 0; ni < 4; ++ni)
            bfr[ni] = *reinterpret_cast<const bf16x8*>(
                &lds[1][(wc * 64 + ni * 16 + (lane & 15)) * 32 + (lane >> 4) * 8]);
        #pragma unroll
        for (int mi = 0; mi < 4; ++mi)
            #pragma unroll
            for (int ni = 0; ni < 4; ++ni)
                acc[mi][ni] = __builtin_amdgcn_mfma_f32_16x16x32_bf16(af[mi], bfr[ni], acc[mi][ni], 0, 0, 0);
        __syncthreads();
    }

    const int rbase = bm0 + wr * 64 + (lane >> 4) * 4;
    const int cbase = bn0 + wc * 64 + (lane & 15);

    if constexpr (EPI == 1) {
        const float v0 = topv[0], v1 = topv[1];
        const bf16x8 z8 = {};
        bf16x8 bl0[4], bl1[4];
        #pragma unroll
        for (int ni = 0; ni < 4; ++ni) {
            const int f = cbase + ni * 16;
            bf16x8 bfull = *reinterpret_cast<const bf16x8*>(&bcat[(size_t)f * 32 + (lane >> 4) * 8]);
            bl0[ni] = ((lane >> 4) < 2) ? bfull : z8;   // [B0 | 0]
            bl1[ni] = ((lane >> 4) < 2) ? z8 : bfull;   // [0 | B1]
        }
        #pragma unroll
        for (int mi = 0; mi < 4; ++mi) {
            const int mrow = bm0 + wr * 64 + mi * 16 + (lane & 15);
            const bf16x8 alo = *reinterpret_cast<const bf16x8*>(&tcat[(size_t)mrow * 32 + (lane >> 4) * 8]);
            #pragma unroll
            for (int ni = 0; ni < 4; ++ni) {
                const f32x4 zz = {};
                f32x4 l0 = __builtin_amdgcn_mfma_f32_16x16x32_bf16(alo, bl0[ni], zz, 0, 0, 0);
                f32x4 l1 = __builtin_amdgcn_mfma_f32_16x16x32_bf16(alo, bl1[ni], zz, 0, 0, 0);
                #pragma unroll
                for (int j = 0; j < 4; ++j) {
                    float z = acc[mi][ni][j];
                    float c = v0 * fmaxf(z + l0[j], 0.f) + v1 * fmaxf(z + l1[j], 0.f);
                    outBf[(size_t)(rbase + mi * 16 + j) * OSTRIDE + cbase + ni * 16] = f2bf(c);
                }
            }
        }
    } else {
        #pragma unroll
        for (int mi = 0; mi < 4; ++mi)
            #pragma unroll
            for (int ni = 0; ni < 4; ++ni)
                #pragma unroll
                for (int j = 0; j < 4; ++j)
                    outF[(size_t)(rbase + mi * 16 + j) * OSTRIDE + cbase + ni * 16] = acc[mi][ni][j];
    }
}

extern "C" void kernel_launch(void* const* d_in, const int* in_sizes, int n_in,
                              void* d_out, int out_size, void* d_ws, size_t ws_size,
                              hipStream_t stream) {
    const float* h    = (const float*)d_in[0];
    const float* wi   = (const float*)d_in[1];
    const float* wo   = (const float*)d_in[2];
    const float* As   = (const float*)d_in[3];
    const float* Bs   = (const float*)d_in[4];
    const int*   idx  = (const int*)d_in[5];
    const float* topv = (const float*)d_in[6];
    float* out = (float*)d_out;

    char* ws = (char*)d_ws;
    unsigned short* hbf  = (unsigned short*)(ws);                       // 16384x1024 bf16 = 32MB
    unsigned short* wibf = (unsigned short*)(ws + 33554432);            // 4096x1024  bf16 =  8MB
    unsigned short* wobf = (unsigned short*)(ws + 41943040);            // 1024x4096  bf16 =  8MB
    unsigned short* tcat = (unsigned short*)(ws + 50331648);            // 16384x32   bf16 =  1MB
    unsigned short* bcat = (unsigned short*)(ws + 51380224);            // 4096x32    bf16 = .25MB
    unsigned short* comb = (unsigned short*)(ws + 51642368);            // 16384x4096 bf16 = 128MB

    cast_kernel<<<2048, 256, 0, stream>>>(h,  hbf,  (NTOK * D_MODEL) / 4);
    cast_kernel<<<1024, 256, 0, stream>>>(wi, wibf, (D_FF * D_MODEL) / 4);
    cast_kernel<<<1024, 256, 0, stream>>>(wo, wobf, (D_MODEL * D_FF) / 4);
    lora_t_kernel<<<NTOK, 64, 0, stream>>>(h, As, idx, tcat);
    bcat_kernel<<<(D_FF * 32) / 256, 256, 0, stream>>>(Bs, idx, bcat);

    // gemm1: combined = sum_k v_k * relu(h@Wi^T + t_k@B_k^T)   [16384 x 4096] bf16
    gemm_bt<D_MODEL, 1, D_FF><<<dim3(NTOK / 128, D_FF / 128), 256, 0, stream>>>(
        hbf, wibf, nullptr, comb, tcat, bcat, topv);
    // gemm2: out = combined @ Wo^T                              [16384 x 1024] fp32
    gemm_bt<D_FF, 0, D_MODEL><<<dim3(NTOK / 128, D_MODEL / 128), 256, 0, stream>>>(
        comb, wobf, out, nullptr, nullptr, nullptr, nullptr);
}

// Round 2
// 348.180 us; speedup vs baseline: 1.2603x; 1.2603x over previous
//
#include <hip/hip_runtime.h>
#include <hip/hip_bf16.h>
#include <cstdint>
#include <cstddef>

#define D_MODEL 1024
#define D_FF    4096
#define RANK    16
#define NTOK    16384   // B*S = 8*2048

typedef __attribute__((ext_vector_type(8))) __bf16 bf16x8;
typedef __attribute__((ext_vector_type(4))) float  f32x4;

using gas_t = const __attribute__((address_space(1))) void*;
using las_t = __attribute__((address_space(3))) void*;

__device__ __forceinline__ unsigned short f2bf(float f) {
    unsigned int u = __builtin_bit_cast(unsigned int, f);
    u += 0x7fffu + ((u >> 16) & 1u);
    return (unsigned short)(u >> 16);
}

__device__ __forceinline__ void gload_lds16(const unsigned short* g, unsigned short* l) {
    __builtin_amdgcn_global_load_lds((gas_t)g, (las_t)l, 16, 0, 0);
}

// ---- fp32 -> bf16 cast, vectorized ----
__global__ void cast_kernel(const float* __restrict__ in, unsigned short* __restrict__ out, int n4) {
    int i = blockIdx.x * blockDim.x + threadIdx.x;
    int stride = gridDim.x * blockDim.x;
    for (; i < n4; i += stride) {
        float4 v = reinterpret_cast<const float4*>(in)[i];
        ushort4 o;
        o.x = f2bf(v.x); o.y = f2bf(v.y); o.z = f2bf(v.z); o.w = f2bf(v.w);
        reinterpret_cast<ushort4*>(out)[i] = o;
    }
}

// ---- t_k[m][r] = sum_d h[m][d]*A_{idx_k}[r][d] (packed [t0|t1], bf16) + h->bf16 cast fused ----
__global__ void lora_t_kernel(const float* __restrict__ h, const float* __restrict__ As,
                              const int* __restrict__ idx, unsigned short* __restrict__ tcat,
                              unsigned short* __restrict__ hbf) {
    const int m = blockIdx.x;
    const int l = threadIdx.x;
    float hreg[16];
    #pragma unroll
    for (int j = 0; j < 16; ++j) hreg[j] = h[(size_t)m * D_MODEL + j * 64 + l];
    #pragma unroll
    for (int j = 0; j < 16; ++j) hbf[(size_t)m * D_MODEL + j * 64 + l] = f2bf(hreg[j]);
    #pragma unroll
    for (int e = 0; e < 2; ++e) {
        const float* A = As + (size_t)idx[e] * RANK * D_MODEL;
        for (int r = 0; r < RANK; ++r) {
            float s = 0.f;
            #pragma unroll
            for (int j = 0; j < 16; ++j) s += hreg[j] * A[r * D_MODEL + j * 64 + l];
            #pragma unroll
            for (int off = 32; off >= 1; off >>= 1) s += __shfl_xor(s, off, 64);
            if (l == 0) tcat[(size_t)m * 32 + e * 16 + r] = f2bf(s);
        }
    }
}

// ---- Bcat[f][e*16+r] = bf16(lora_Bs[idx_e][f][r]) ----
__global__ void bcat_kernel(const float* __restrict__ Bs, const int* __restrict__ idx,
                            unsigned short* __restrict__ bcat) {
    int i = blockIdx.x * blockDim.x + threadIdx.x;   // over D_FF*32
    if (i >= D_FF * 32) return;
    int f = i >> 5, kk = i & 31;
    int e = kk >> 4, r = kk & 15;
    bcat[i] = f2bf(Bs[(size_t)idx[e] * D_FF * RANK + (size_t)f * RANK + r]);
}

// ============================================================================
// 256x256 8-phase GEMM: C = A[M][K] x B[N][K]^T, bf16 MFMA 16x16x32.
// 8 waves (2M x 4N), per-wave 128x64 output, BK=64 (2 K-tiles per iteration).
// LDS [buf][A/B][half][128][64] bf16 = 128 KiB, T2-swizzled (col ^= (row&7)<<3)
// via pre-swizzled global source (linear global_load_lds dest) + swizzled read.
// Counted vmcnt(4) at P4/P8 only; setprio around MFMA clusters; XCD swizzle.
// ============================================================================
template<int KDIM, int EPI, int OSTRIDE, int GN>
__launch_bounds__(512, 2)
__global__ void gemm256(const unsigned short* __restrict__ A,
                        const unsigned short* __restrict__ Bm,
                        float* __restrict__ outF,
                        unsigned short* __restrict__ outBf,
                        const unsigned short* __restrict__ tcat,
                        const unsigned short* __restrict__ bcat,
                        const float* __restrict__ topv) {
    __shared__ unsigned short lds[2][2][2][128 * 64];
    const int tid  = threadIdx.x;
    const int lane = tid & 63;
    const int wid  = tid >> 6;        // 0..7
    const int wr   = wid >> 2;        // 0..1  (M half owned by this wave)
    const int wc   = wid & 3;         // 0..3
    const int lr   = lane & 15;
    const int hi   = lane >> 4;       // 0..3
    const int swz  = (lane & 7) << 3; // read-side col swizzle

    // bijective XCD swizzle (nwg % 8 == 0 for both launches)
    const int nwg  = gridDim.x;
    const int orig = blockIdx.x;
    const int wg   = (orig & 7) * (nwg >> 3) + (orig >> 3);
    const int bm0  = (wg / GN) * 256;
    const int bn0  = (wg % GN) * 256;

    constexpr int NKT = KDIM / 64;
    constexpr int NT2 = NKT / 2;

    f32x4 acc[8][4] = {};
    bf16x8 aF[8], b0[4], b1[4];

    auto stage = [&](int buf, int mat, int half, const unsigned short* src, int kt) {
        const int row0 = (mat == 0 ? bm0 : bn0) + half * 128;
        const int k0 = kt * 64;
        #pragma unroll
        for (int p = 0; p < 2; ++p) {
            const int L = p * 8192 + tid * 16;           // byte offset in half-tile
            const int r = L >> 7;                        // row (128B rows)
            const int c = (L & 127) >> 1;                // element col of linear slot
            const int gc = k0 + (c ^ ((r & 7) << 3));    // inverse-swizzled global col
            gload_lds16(src + (size_t)(row0 + r) * KDIM + gc,
                        &lds[buf][mat][half][0] + (L >> 1));
        }
    };
    auto readA = [&](int buf, int qm) {
        #pragma unroll
        for (int fr = 0; fr < 4; ++fr)
            #pragma unroll
            for (int ks = 0; ks < 2; ++ks)
                aF[fr * 2 + ks] = *reinterpret_cast<const bf16x8*>(
                    &lds[buf][0][wr][(qm * 64 + fr * 16 + lr) * 64 + ((ks * 32 + hi * 8) ^ swz)]);
    };
    auto readB = [&](int buf, int qn, bf16x8* bb) {
        #pragma unroll
        for (int fc = 0; fc < 2; ++fc)
            #pragma unroll
            for (int ks = 0; ks < 2; ++ks)
                bb[fc * 2 + ks] = *reinterpret_cast<const bf16x8*>(
                    &lds[buf][1][wc >> 1][((wc & 1) * 64 + qn * 32 + fc * 16 + lr) * 64
                                          + ((ks * 32 + hi * 8) ^ swz)]);
    };
    auto mfma16 = [&](int qm, int qn, const bf16x8* bb) {
        #pragma unroll
        for (int fr = 0; fr < 4; ++fr)
            #pragma unroll
            for (int fc = 0; fc < 2; ++fc)
                #pragma unroll
                for (int ks = 0; ks < 2; ++ks)
                    acc[qm * 4 + fr][qn * 2 + fc] = __builtin_amdgcn_mfma_f32_16x16x32_bf16(
                        aF[fr * 2 + ks], bb[fc * 2 + ks], acc[qm * 4 + fr][qn * 2 + fc], 0, 0, 0);
    };

#define BAR() __builtin_amdgcn_s_barrier()
#define WAIT_LGKM() do { asm volatile("s_waitcnt lgkmcnt(0)" ::: "memory"); \
                         __builtin_amdgcn_sched_barrier(0); } while (0)
#define WAIT_VM(n) do { asm volatile("s_waitcnt vmcnt(" #n ")" ::: "memory"); \
                        __builtin_amdgcn_sched_barrier(0); } while (0)
#define PRIO_MFMA(qm, qn, bb) do { __builtin_amdgcn_s_setprio(1); mfma16(qm, qn, bb); \
                                   __builtin_amdgcn_s_setprio(0); } while (0)

    // Prologue: tile0 (all 4 halves) -> bufA; tile1 B-halves -> bufB.
    stage(0, 0, 0, A, 0);  stage(0, 0, 1, A, 0);
    stage(0, 1, 0, Bm, 0); stage(0, 1, 1, Bm, 0);
    stage(1, 1, 0, Bm, 1); stage(1, 1, 1, Bm, 1);
    WAIT_VM(4);
    BAR();

    #pragma unroll 1
    for (int it = 0; it < NT2; ++it) {
        const int t1 = 2 * it + 1;
        const int t2 = (2 * it + 2 < NKT) ? 2 * it + 2 : NKT - 1;  // clamp: dummy, never read
        const int t3 = (2 * it + 3 < NKT) ? 2 * it + 3 : NKT - 1;
        // P1: quad(0,0) from bufA; stage bufB.A-top (tile t1)
        readA(0, 0); readB(0, 0, b0);
        stage(1, 0, 0, A, t1);
        BAR(); WAIT_LGKM(); PRIO_MFMA(0, 0, b0); BAR();
        // P2: quad(0,1); stage bufB.A-bot (t1)
        readB(0, 1, b1);
        stage(1, 0, 1, A, t1);
        BAR(); WAIT_LGKM(); PRIO_MFMA(0, 1, b1); BAR();
        // P3: quad(1,0); stage bufA.B-top (t2)  [bufA.B free after P2]
        readA(0, 1);
        stage(0, 1, 0, Bm, t2);
        BAR(); WAIT_LGKM(); PRIO_MFMA(1, 0, b0); BAR();
        // P4: quad(1,1); stage bufA.B-bot (t2); vmcnt(4) -> tile t1 fully staged
        stage(0, 1, 1, Bm, t2);
        BAR(); PRIO_MFMA(1, 1, b1); WAIT_VM(4); BAR();
        // P5: quad(0,0) from bufB; stage bufA.A-top (t2)  [bufA.A free after P3]
        readA(1, 0); readB(1, 0, b0);
        stage(0, 0, 0, A, t2);
        BAR(); WAIT_LGKM(); PRIO_MFMA(0, 0, b0); BAR();
        // P6: quad(0,1); stage bufA.A-bot (t2)
        readB(1, 1, b1);
        stage(0, 0, 1, A, t2);
        BAR(); WAIT_LGKM(); PRIO_MFMA(0, 1, b1); BAR();
        // P7: quad(1,0); stage bufB.B-top (t3)  [bufB.B free after P6]
        readA(1, 1);
        stage(1, 1, 0, Bm, t3);
        BAR(); WAIT_LGKM(); PRIO_MFMA(1, 0, b0); BAR();
        // P8: quad(1,1); stage bufB.B-bot (t3); vmcnt(4) -> tile t2 fully staged
        stage(1, 1, 1, Bm, t3);
        BAR(); PRIO_MFMA(1, 1, b1); WAIT_VM(4); BAR();
    }
    asm volatile("s_waitcnt vmcnt(0)" ::: "memory");
    __builtin_amdgcn_sched_barrier(0);
    BAR();

    // ---- epilogue ----
    const int rbase = bm0 + wr * 128 + hi * 4;
    const int cbase = bn0 + wc * 64 + lr;

    if constexpr (EPI == 1) {
        const float v0 = topv[0], v1 = topv[1];
        const bf16x8 z8 = {};
        bf16x8 bl0[4], bl1[4];
        #pragma unroll
        for (int ni = 0; ni < 4; ++ni) {
            const int f = cbase + ni * 16;
            bf16x8 bfull = *reinterpret_cast<const bf16x8*>(&bcat[(size_t)f * 32 + hi * 8]);
            bl0[ni] = (hi < 2) ? bfull : z8;   // [B0 | 0]
            bl1[ni] = (hi < 2) ? z8 : bfull;   // [0 | B1]
        }
        #pragma unroll
        for (int mi = 0; mi < 8; ++mi) {
            const int mrow = bm0 + wr * 128 + mi * 16 + lr;
            const bf16x8 alo = *reinterpret_cast<const bf16x8*>(&tcat[(size_t)mrow * 32 + hi * 8]);
            #pragma unroll
            for (int ni = 0; ni < 4; ++ni) {
                const f32x4 zz = {};
                f32x4 l0 = __builtin_amdgcn_mfma_f32_16x16x32_bf16(alo, bl0[ni], zz, 0, 0, 0);
                f32x4 l1 = __builtin_amdgcn_mfma_f32_16x16x32_bf16(alo, bl1[ni], zz, 0, 0, 0);
                #pragma unroll
                for (int j = 0; j < 4; ++j) {
                    float z = acc[mi][ni][j];
                    float c = v0 * fmaxf(z + l0[j], 0.f) + v1 * fmaxf(z + l1[j], 0.f);
                    outBf[(size_t)(rbase + mi * 16 + j) * OSTRIDE + cbase + ni * 16] = f2bf(c);
                }
            }
        }
    } else {
        #pragma unroll
        for (int mi = 0; mi < 8; ++mi)
            #pragma unroll
            for (int ni = 0; ni < 4; ++ni)
                #pragma unroll
                for (int j = 0; j < 4; ++j)
                    outF[(size_t)(rbase + mi * 16 + j) * OSTRIDE + cbase + ni * 16] = acc[mi][ni][j];
    }
#undef BAR
#undef WAIT_LGKM
#undef WAIT_VM
#undef PRIO_MFMA
}

extern "C" void kernel_launch(void* const* d_in, const int* in_sizes, int n_in,
                              void* d_out, int out_size, void* d_ws, size_t ws_size,
                              hipStream_t stream) {
    const float* h    = (const float*)d_in[0];
    const float* wi   = (const float*)d_in[1];
    const float* wo   = (const float*)d_in[2];
    const float* As   = (const float*)d_in[3];
    const float* Bs   = (const float*)d_in[4];
    const int*   idx  = (const int*)d_in[5];
    const float* topv = (const float*)d_in[6];
    float* out = (float*)d_out;

    char* ws = (char*)d_ws;
    unsigned short* hbf  = (unsigned short*)(ws);                       // 16384x1024 bf16 = 32MB
    unsigned short* wibf = (unsigned short*)(ws + 33554432);            // 4096x1024  bf16 =  8MB
    unsigned short* wobf = (unsigned short*)(ws + 41943040);            // 1024x4096  bf16 =  8MB
    unsigned short* tcat = (unsigned short*)(ws + 50331648);            // 16384x32   bf16 =  1MB
    unsigned short* bcat = (unsigned short*)(ws + 51380224);            // 4096x32    bf16 = .25MB
    unsigned short* comb = (unsigned short*)(ws + 51642368);            // 16384x4096 bf16 = 128MB

    lora_t_kernel<<<NTOK, 64, 0, stream>>>(h, As, idx, tcat, hbf);      // also casts h->bf16
    cast_kernel<<<1024, 256, 0, stream>>>(wi, wibf, (D_FF * D_MODEL) / 4);
    cast_kernel<<<1024, 256, 0, stream>>>(wo, wobf, (D_MODEL * D_FF) / 4);
    bcat_kernel<<<(D_FF * 32) / 256, 256, 0, stream>>>(Bs, idx, bcat);

    // gemm1: comb = sum_k v_k * relu(h@Wi^T + t_k@B_k^T)   [16384 x 4096] bf16
    gemm256<D_MODEL, 1, D_FF, 16><<<dim3(64 * 16), 512, 0, stream>>>(
        hbf, wibf, nullptr, comb, tcat, bcat, topv);
    // gemm2: out = comb @ Wo^T                              [16384 x 1024] fp32
    gemm256<D_FF, 0, D_MODEL, 4><<<dim3(64 * 4), 512, 0, stream>>>(
        comb, wobf, out, nullptr, nullptr, nullptr, nullptr);
}